// Round 12
// baseline (249.500 us; speedup 1.0000x reference)
//
#include <hip/hip_runtime.h>
#include <hip/hip_bf16.h>
#include <stdint.h>

#define T_DIM 256
#define U_DIM 64
#define D_DIM 512
#define NIN 512
#define NV 4096

typedef __bf16 bf16x8 __attribute__((ext_vector_type(8)));
typedef float f32x4 __attribute__((ext_vector_type(4)));

static __device__ __forceinline__ unsigned short f2bf(float x) {
  union { float f; unsigned int u; } v; v.f = x;
  unsigned int r = v.u + 0x7FFFu + ((v.u >> 16) & 1u);
  return (unsigned short)(r >> 16);
}

static __device__ __forceinline__ void gload_lds16(const unsigned short* g, void* l) {
  __builtin_amdgcn_global_load_lds(
      (__attribute__((address_space(1))) void*)(unsigned short*)g,
      (__attribute__((address_space(3))) void*)l, 16, 0, 0);
}

// ---------------- fused prep: blocks 0..1023 convert W2; blocks 1024..1063 proj ----------------
__global__ __launch_bounds__(256) void prep_kernel(const float* __restrict__ W2,
                                                   unsigned short* __restrict__ W2b,
                                                   const float* __restrict__ enc,
                                                   const float* __restrict__ dec,
                                                   const float* __restrict__ W1,
                                                   float* __restrict__ ep0,
                                                   float* __restrict__ ep1,
                                                   float* __restrict__ dp0,
                                                   float* __restrict__ dp1) {
  __shared__ unsigned short As[128 * 32];
  __shared__ unsigned short Bs[128 * 32];
  const int tid = threadIdx.x;

  if (blockIdx.x < 1024) {
    int q = blockIdx.x * 256 + tid;
    const float4 v0 = *(const float4*)(W2 + (size_t)q * 8);
    const float4 v1 = *(const float4*)(W2 + (size_t)q * 8 + 4);
    union { unsigned short s[8]; uint4 u; } o;
    o.s[0] = f2bf(v0.x); o.s[1] = f2bf(v0.y); o.s[2] = f2bf(v0.z); o.s[3] = f2bf(v0.w);
    o.s[4] = f2bf(v1.x); o.s[5] = f2bf(v1.y); o.s[6] = f2bf(v1.z); o.s[7] = f2bf(v1.w);
    *(uint4*)(W2b + (size_t)q * 8) = o.u;
    return;
  }

  const int pbid = blockIdx.x - 1024;
  const int tile_m = pbid >> 3;
  const int kh = (pbid >> 2) & 1;
  const int tile_n = pbid & 3;
  const bool is_dec = (tile_m == 4);
  const float* X = is_dec ? dec : enc;
  const int xrow0 = is_dec ? 0 : tile_m * 128;
  const int wcol0 = is_dec ? D_DIM : 0;
  float* outp = is_dec ? (kh ? dp1 : dp0) : (kh ? ep1 : ep0);

  const int lane = tid & 63;
  const int wv = tid >> 6;
  const int wr = wv >> 1, wc = wv & 1;
  const int arow = tid >> 1;
  const int acol = (tid & 1) * 16;

  f32x4 acc[4][4] = {};

  const float* pa = X + (size_t)(xrow0 + arow) * D_DIM + acol;
  const float* pb = W1 + (size_t)(tile_n * 128 + arow) * (2 * D_DIM) + wcol0 + acol;

  for (int k0 = kh * 256; k0 < kh * 256 + 256; k0 += 32) {
    float4 av0 = *(const float4*)(pa + k0);
    float4 av1 = *(const float4*)(pa + k0 + 4);
    float4 av2 = *(const float4*)(pa + k0 + 8);
    float4 av3 = *(const float4*)(pa + k0 + 12);
    float4 bv0 = *(const float4*)(pb + k0);
    float4 bv1 = *(const float4*)(pb + k0 + 4);
    float4 bv2 = *(const float4*)(pb + k0 + 8);
    float4 bv3 = *(const float4*)(pb + k0 + 12);
    __syncthreads();
    union { unsigned short s[8]; uint4 u; } u0, u1, w0, w1;
    u0.s[0] = f2bf(av0.x); u0.s[1] = f2bf(av0.y); u0.s[2] = f2bf(av0.z); u0.s[3] = f2bf(av0.w);
    u0.s[4] = f2bf(av1.x); u0.s[5] = f2bf(av1.y); u0.s[6] = f2bf(av1.z); u0.s[7] = f2bf(av1.w);
    u1.s[0] = f2bf(av2.x); u1.s[1] = f2bf(av2.y); u1.s[2] = f2bf(av2.z); u1.s[3] = f2bf(av2.w);
    u1.s[4] = f2bf(av3.x); u1.s[5] = f2bf(av3.y); u1.s[6] = f2bf(av3.z); u1.s[7] = f2bf(av3.w);
    w0.s[0] = f2bf(bv0.x); w0.s[1] = f2bf(bv0.y); w0.s[2] = f2bf(bv0.z); w0.s[3] = f2bf(bv0.w);
    w0.s[4] = f2bf(bv1.x); w0.s[5] = f2bf(bv1.y); w0.s[6] = f2bf(bv1.z); w0.s[7] = f2bf(bv1.w);
    w1.s[0] = f2bf(bv2.x); w1.s[1] = f2bf(bv2.y); w1.s[2] = f2bf(bv2.z); w1.s[3] = f2bf(bv2.w);
    w1.s[4] = f2bf(bv3.x); w1.s[5] = f2bf(bv3.y); w1.s[6] = f2bf(bv3.z); w1.s[7] = f2bf(bv3.w);
    *(uint4*)&As[arow * 32 + acol] = u0.u;
    *(uint4*)&As[arow * 32 + acol + 8] = u1.u;
    *(uint4*)&Bs[arow * 32 + acol] = w0.u;
    *(uint4*)&Bs[arow * 32 + acol + 8] = w1.u;
    __syncthreads();
    bf16x8 af[4], bff[4];
#pragma unroll
    for (int mi = 0; mi < 4; ++mi)
      af[mi] = *(const bf16x8*)&As[(wr * 64 + mi * 16 + (lane & 15)) * 32 + (lane >> 4) * 8];
#pragma unroll
    for (int ni = 0; ni < 4; ++ni)
      bff[ni] = *(const bf16x8*)&Bs[(wc * 64 + ni * 16 + (lane & 15)) * 32 + (lane >> 4) * 8];
#pragma unroll
    for (int mi = 0; mi < 4; ++mi)
#pragma unroll
      for (int ni = 0; ni < 4; ++ni)
        acc[mi][ni] = __builtin_amdgcn_mfma_f32_16x16x32_bf16(af[mi], bff[ni], acc[mi][ni], 0, 0, 0);
  }

#pragma unroll
  for (int mi = 0; mi < 4; ++mi) {
#pragma unroll
    for (int r = 0; r < 4; ++r) {
      int row = xrow0 + wr * 64 + mi * 16 + ((lane >> 4) << 2) + r;
      float* po = outp + (size_t)row * NIN + tile_n * 128 + wc * 64 + (lane & 15);
#pragma unroll
      for (int ni = 0; ni < 4; ++ni) po[ni * 16] = acc[mi][ni][r];
    }
  }
}

// ---------------- H = tanh(ep0+ep1[bt] + dp0+dp1[bu] + b1) -> bf16 ----------------
__global__ __launch_bounds__(256) void h_kernel(const float* __restrict__ ep0,
                                                const float* __restrict__ ep1,
                                                const float* __restrict__ dp0,
                                                const float* __restrict__ dp1,
                                                const float* __restrict__ b1,
                                                unsigned short* __restrict__ Hb) {
  int q = blockIdx.x * 256 + threadIdx.x;
  int m = q >> 6;
  int i0 = (q & 63) << 3;
  size_t eoff = (size_t)(m >> 6) * NIN + i0;
  size_t doff = (size_t)((m >> 14) * U_DIM + (m & 63)) * NIN + i0;
  float4 e0 = *(const float4*)(ep0 + eoff);
  float4 e1 = *(const float4*)(ep0 + eoff + 4);
  float4 f0 = *(const float4*)(ep1 + eoff);
  float4 f1 = *(const float4*)(ep1 + eoff + 4);
  float4 d0 = *(const float4*)(dp0 + doff);
  float4 d1 = *(const float4*)(dp0 + doff + 4);
  float4 g0 = *(const float4*)(dp1 + doff);
  float4 g1 = *(const float4*)(dp1 + doff + 4);
  float4 c0 = *(const float4*)(b1 + i0);
  float4 c1 = *(const float4*)(b1 + i0 + 4);
  float x[8] = { e0.x + f0.x + d0.x + g0.x + c0.x, e0.y + f0.y + d0.y + g0.y + c0.y,
                 e0.z + f0.z + d0.z + g0.z + c0.z, e0.w + f0.w + d0.w + g0.w + c0.w,
                 e1.x + f1.x + d1.x + g1.x + c1.x, e1.y + f1.y + d1.y + g1.y + c1.y,
                 e1.z + f1.z + d1.z + g1.z + c1.z, e1.w + f1.w + d1.w + g1.w + c1.w };
  union { unsigned short s[8]; uint4 u; } o;
#pragma unroll
  for (int j = 0; j < 8; ++j) {
    float ex = __expf(2.0f * x[j]);
    float t = 1.0f - 2.0f / (ex + 1.0f);
    o.s[j] = f2bf(t);
  }
  *(uint4*)(Hb + (size_t)q * 8) = o.u;
}

// ---------------- main GEMM: out = H @ W2b^T + b2 ----------------
// R10 base (256x128 tile, 4 waves 128x64, 3-stage A pipeline, supertile L2 map,
// NT stores) with B REMOVED FROM LDS: B fragments loaded direct global->reg
// (identity mapping row=lane&15, seg=lane>>4 — algebraically equal to the old
// stage+read swizzle pair), register double-buffered (bqA/bqB), issued 1 iter
// ahead (~400cy >= L2 latency; B is L2-resident, FETCH 82MB proven).
// LDS = A only: 3 x 16KB = 48KB, traffic 72->48KB/iter; 2 blocks/CU (the
// R10-vs-R11 proven co-residency lever). One barrier/iter; in-order-derived
// counted vmcnt: k=0 ->4, k=1..14 ->8, k=15 ->4.
__global__ __launch_bounds__(256, 2) void gemm_kernel(const unsigned short* __restrict__ Hb,
                                                      const unsigned short* __restrict__ W2b,
                                                      const float* __restrict__ b2,
                                                      float* __restrict__ out) {
  __shared__ __align__(16) char smem[49152];  // A: 3 stages x 16KB
  const int tid = threadIdx.x;
  const int lane = tid & 63;
  const int wv = tid >> 6;
  const int wr = wv >> 1, wc = wv & 1;   // wave tile: rows wr*128, cols wc*64
  const int bid = blockIdx.x;

  // XCD chunk + 4x8 supertile mapping (grid 4096 = 8 XCD x 512) — R10-proven
  const int xcd = bid & 7;
  const int idx = bid >> 3;
  const int sup = idx >> 5;
  const int within = idx & 31;
  const int tm = (xcd << 4) | ((sup >> 2) << 2) | (within >> 3);  // 0..127
  const int tn = ((sup & 3) << 3) | (within & 7);                 // 0..31
  const int m0 = tm * 256, n0 = tn * 128;

  // A staging source (pre-swizzled seg-rot, proven identity with laneA read)
  const int srow = tid >> 2;
  const int segp = ((((tid & 3) - ((tid >> 3) & 3)) & 3) << 3);
  const unsigned short* pA = Hb + (size_t)(m0 + srow) * 512 + segp;
  const int dstOff = tid << 4;
  const int laneA = ((lane & 15) << 6) | ((((lane >> 4) + ((lane >> 1) & 7)) & 3) << 4);

  // B direct fragment base: row = n0 + wc*64 + ni*16 + (lane&15), k-seg = lane>>4
  const unsigned short* pBd = W2b + (size_t)(n0 + wc * 64 + (lane & 15)) * 512 + ((lane >> 4) << 3);

  f32x4 acc[8][4] = {};
  bf16x8 af[8], bqA[4], bqB[4];

  // b2 loaded first (drained by the first counted vmcnt)
  float b2v[4];
#pragma unroll
  for (int ni = 0; ni < 4; ++ni) b2v[ni] = b2[n0 + wc * 64 + ni * 16 + (lane & 15)];

#define STAGE(T, BUF) do { \
    gload_lds16(pA + (size_t)(T) * 32,             smem + (BUF) * 16384 + dstOff); \
    gload_lds16(pA + (size_t)(T) * 32 + 64 * 512,  smem + (BUF) * 16384 + 4096 + dstOff); \
    gload_lds16(pA + (size_t)(T) * 32 + 128 * 512, smem + (BUF) * 16384 + 8192 + dstOff); \
    gload_lds16(pA + (size_t)(T) * 32 + 192 * 512, smem + (BUF) * 16384 + 12288 + dstOff); \
  } while (0)
#define BAR() __builtin_amdgcn_s_barrier()
#define SCHED0() __builtin_amdgcn_sched_barrier(0)
#define VMCNT_(N) asm volatile("s_waitcnt vmcnt(" #N ")" ::: "memory")
#define VMCNT(N) VMCNT_(N)

#define LOADB(DST, K) do { \
    _Pragma("unroll") for (int ni = 0; ni < 4; ++ni) \
      DST[ni] = *(const bf16x8*)(pBd + (size_t)ni * 16 * 512 + (K) * 32); \
  } while (0)

// One k-step. K literal; W = vmcnt literal; CURB = this iter's B regs;
// NXTB = next iter's B regs (loaded here, 1 iter ahead).
#define ITER(K, W, CURB, NXTB) do { \
    VMCNT(W); \
    BAR(); \
    SCHED0(); \
    if ((K) < 15) { LOADB(NXTB, (K) + 1); } \
    if ((K) < 14) { STAGE((K) + 2, ((K) + 2) % 3); } \
    _Pragma("unroll") for (int mi = 0; mi < 8; ++mi) \
      af[mi] = *(const bf16x8*)(smem + ((K) % 3) * 16384 + ((wr * 8 + mi) << 10) + laneA); \
    __builtin_amdgcn_s_setprio(1); \
    _Pragma("unroll") for (int mi = 0; mi < 8; ++mi) \
      _Pragma("unroll") for (int ni = 0; ni < 4; ++ni) \
        acc[mi][ni] = __builtin_amdgcn_mfma_f32_16x16x32_bf16(af[mi], CURB[ni], acc[mi][ni], 0, 0, 0); \
    __builtin_amdgcn_s_setprio(0); \
  } while (0)

  // prologue: B(0) -> bqA; stage tiles 0,1
  LOADB(bqA, 0);
  STAGE(0, 0);
  STAGE(1, 1);

  ITER(0, 4, bqA, bqB);
  ITER(1, 8, bqB, bqA);
  ITER(2, 8, bqA, bqB);
  ITER(3, 8, bqB, bqA);
  ITER(4, 8, bqA, bqB);
  ITER(5, 8, bqB, bqA);
  ITER(6, 8, bqA, bqB);
  ITER(7, 8, bqB, bqA);
  ITER(8, 8, bqA, bqB);
  ITER(9, 8, bqB, bqA);
  ITER(10, 8, bqA, bqB);
  ITER(11, 8, bqB, bqA);
  ITER(12, 8, bqA, bqB);
  ITER(13, 8, bqB, bqA);
  ITER(14, 8, bqA, bqB);
  ITER(15, 4, bqB, bqA);

#undef STAGE
#undef BAR
#undef SCHED0
#undef VMCNT_
#undef VMCNT
#undef LOADB
#undef ITER

  // epilogue: C = acc + b2, NT stores (keep 512MB stream out of L2/L3 — proven)
#pragma unroll
  for (int mi = 0; mi < 8; ++mi) {
#pragma unroll
    for (int r = 0; r < 4; ++r) {
      int row = m0 + wr * 128 + mi * 16 + ((lane >> 4) << 2) + r;
      float* po = out + (size_t)row * NV + n0 + wc * 64 + (lane & 15);
#pragma unroll
      for (int ni = 0; ni < 4; ++ni)
        __builtin_nontemporal_store(acc[mi][ni][r] + b2v[ni], po + ni * 16);
    }
  }
}

extern "C" void kernel_launch(void* const* d_in, const int* in_sizes, int n_in,
                              void* d_out, int out_size, void* d_ws, size_t ws_size,
                              hipStream_t stream) {
  const float* enc = (const float*)d_in[0];
  const float* dec = (const float*)d_in[1];
  const float* W1  = (const float*)d_in[2];
  const float* b1  = (const float*)d_in[3];
  const float* W2  = (const float*)d_in[4];
  const float* b2  = (const float*)d_in[5];
  float* out = (float*)d_out;

  char* ws = (char*)d_ws;
  unsigned short* W2b = (unsigned short*)(ws);                 // 4 MB
  float* ep0 = (float*)(ws + 4194304);                         // 1 MB
  float* ep1 = (float*)(ws + 5242880);                         // 1 MB
  float* dp0 = (float*)(ws + 6291456);                         // 256 KB
  float* dp1 = (float*)(ws + 6553600);                         // 256 KB
  unsigned short* Hb = (unsigned short*)(ws + 6815744);        // 32 MB

  hipLaunchKernelGGL(prep_kernel, dim3(1064), dim3(256), 0, stream,
                     W2, W2b, enc, dec, W1, ep0, ep1, dp0, dp1);
  hipLaunchKernelGGL(h_kernel, dim3(8192), dim3(256), 0, stream, ep0, ep1, dp0, dp1, b1, Hb);
  hipLaunchKernelGGL(gemm_kernel, dim3(4096), dim3(256), 0, stream, Hb, W2b, b2, out);
}

// Round 13
// 196.851 us; speedup vs baseline: 1.2675x; 1.2675x over previous
//
#include <hip/hip_runtime.h>
#include <hip/hip_bf16.h>
#include <stdint.h>

#define T_DIM 256
#define U_DIM 64
#define D_DIM 512
#define NIN 512
#define NV 4096

typedef __bf16 bf16x8 __attribute__((ext_vector_type(8)));
typedef float f32x4 __attribute__((ext_vector_type(4)));

static __device__ __forceinline__ unsigned short f2bf(float x) {
  union { float f; unsigned int u; } v; v.f = x;
  unsigned int r = v.u + 0x7FFFu + ((v.u >> 16) & 1u);
  return (unsigned short)(r >> 16);
}

static __device__ __forceinline__ void gload_lds16(const unsigned short* g, void* l) {
  __builtin_amdgcn_global_load_lds(
      (__attribute__((address_space(1))) void*)(unsigned short*)g,
      (__attribute__((address_space(3))) void*)l, 16, 0, 0);
}

// ---------------- fused prep: blocks 0..1023 convert W2; blocks 1024..1063 proj ----------------
__global__ __launch_bounds__(256) void prep_kernel(const float* __restrict__ W2,
                                                   unsigned short* __restrict__ W2b,
                                                   const float* __restrict__ enc,
                                                   const float* __restrict__ dec,
                                                   const float* __restrict__ W1,
                                                   float* __restrict__ ep0,
                                                   float* __restrict__ ep1,
                                                   float* __restrict__ dp0,
                                                   float* __restrict__ dp1) {
  __shared__ unsigned short As[128 * 32];
  __shared__ unsigned short Bs[128 * 32];
  const int tid = threadIdx.x;

  if (blockIdx.x < 1024) {
    int q = blockIdx.x * 256 + tid;
    const float4 v0 = *(const float4*)(W2 + (size_t)q * 8);
    const float4 v1 = *(const float4*)(W2 + (size_t)q * 8 + 4);
    union { unsigned short s[8]; uint4 u; } o;
    o.s[0] = f2bf(v0.x); o.s[1] = f2bf(v0.y); o.s[2] = f2bf(v0.z); o.s[3] = f2bf(v0.w);
    o.s[4] = f2bf(v1.x); o.s[5] = f2bf(v1.y); o.s[6] = f2bf(v1.z); o.s[7] = f2bf(v1.w);
    *(uint4*)(W2b + (size_t)q * 8) = o.u;
    return;
  }

  const int pbid = blockIdx.x - 1024;
  const int tile_m = pbid >> 3;
  const int kh = (pbid >> 2) & 1;
  const int tile_n = pbid & 3;
  const bool is_dec = (tile_m == 4);
  const float* X = is_dec ? dec : enc;
  const int xrow0 = is_dec ? 0 : tile_m * 128;
  const int wcol0 = is_dec ? D_DIM : 0;
  float* outp = is_dec ? (kh ? dp1 : dp0) : (kh ? ep1 : ep0);

  const int lane = tid & 63;
  const int wv = tid >> 6;
  const int wr = wv >> 1, wc = wv & 1;
  const int arow = tid >> 1;
  const int acol = (tid & 1) * 16;

  f32x4 acc[4][4] = {};

  const float* pa = X + (size_t)(xrow0 + arow) * D_DIM + acol;
  const float* pb = W1 + (size_t)(tile_n * 128 + arow) * (2 * D_DIM) + wcol0 + acol;

  for (int k0 = kh * 256; k0 < kh * 256 + 256; k0 += 32) {
    float4 av0 = *(const float4*)(pa + k0);
    float4 av1 = *(const float4*)(pa + k0 + 4);
    float4 av2 = *(const float4*)(pa + k0 + 8);
    float4 av3 = *(const float4*)(pa + k0 + 12);
    float4 bv0 = *(const float4*)(pb + k0);
    float4 bv1 = *(const float4*)(pb + k0 + 4);
    float4 bv2 = *(const float4*)(pb + k0 + 8);
    float4 bv3 = *(const float4*)(pb + k0 + 12);
    __syncthreads();
    union { unsigned short s[8]; uint4 u; } u0, u1, w0, w1;
    u0.s[0] = f2bf(av0.x); u0.s[1] = f2bf(av0.y); u0.s[2] = f2bf(av0.z); u0.s[3] = f2bf(av0.w);
    u0.s[4] = f2bf(av1.x); u0.s[5] = f2bf(av1.y); u0.s[6] = f2bf(av1.z); u0.s[7] = f2bf(av1.w);
    u1.s[0] = f2bf(av2.x); u1.s[1] = f2bf(av2.y); u1.s[2] = f2bf(av2.z); u1.s[3] = f2bf(av2.w);
    u1.s[4] = f2bf(av3.x); u1.s[5] = f2bf(av3.y); u1.s[6] = f2bf(av3.z); u1.s[7] = f2bf(av3.w);
    w0.s[0] = f2bf(bv0.x); w0.s[1] = f2bf(bv0.y); w0.s[2] = f2bf(bv0.z); w0.s[3] = f2bf(bv0.w);
    w0.s[4] = f2bf(bv1.x); w0.s[5] = f2bf(bv1.y); w0.s[6] = f2bf(bv1.z); w0.s[7] = f2bf(bv1.w);
    w1.s[0] = f2bf(bv2.x); w1.s[1] = f2bf(bv2.y); w1.s[2] = f2bf(bv2.z); w1.s[3] = f2bf(bv2.w);
    w1.s[4] = f2bf(bv3.x); w1.s[5] = f2bf(bv3.y); w1.s[6] = f2bf(bv3.z); w1.s[7] = f2bf(bv3.w);
    *(uint4*)&As[arow * 32 + acol] = u0.u;
    *(uint4*)&As[arow * 32 + acol + 8] = u1.u;
    *(uint4*)&Bs[arow * 32 + acol] = w0.u;
    *(uint4*)&Bs[arow * 32 + acol + 8] = w1.u;
    __syncthreads();
    bf16x8 af[4], bff[4];
#pragma unroll
    for (int mi = 0; mi < 4; ++mi)
      af[mi] = *(const bf16x8*)&As[(wr * 64 + mi * 16 + (lane & 15)) * 32 + (lane >> 4) * 8];
#pragma unroll
    for (int ni = 0; ni < 4; ++ni)
      bff[ni] = *(const bf16x8*)&Bs[(wc * 64 + ni * 16 + (lane & 15)) * 32 + (lane >> 4) * 8];
#pragma unroll
    for (int mi = 0; mi < 4; ++mi)
#pragma unroll
      for (int ni = 0; ni < 4; ++ni)
        acc[mi][ni] = __builtin_amdgcn_mfma_f32_16x16x32_bf16(af[mi], bff[ni], acc[mi][ni], 0, 0, 0);
  }

#pragma unroll
  for (int mi = 0; mi < 4; ++mi) {
#pragma unroll
    for (int r = 0; r < 4; ++r) {
      int row = xrow0 + wr * 64 + mi * 16 + ((lane >> 4) << 2) + r;
      float* po = outp + (size_t)row * NIN + tile_n * 128 + wc * 64 + (lane & 15);
#pragma unroll
      for (int ni = 0; ni < 4; ++ni) po[ni * 16] = acc[mi][ni][r];
    }
  }
}

// ---------------- H = tanh(ep0+ep1[bt] + dp0+dp1[bu] + b1) -> bf16 ----------------
__global__ __launch_bounds__(256) void h_kernel(const float* __restrict__ ep0,
                                                const float* __restrict__ ep1,
                                                const float* __restrict__ dp0,
                                                const float* __restrict__ dp1,
                                                const float* __restrict__ b1,
                                                unsigned short* __restrict__ Hb) {
  int q = blockIdx.x * 256 + threadIdx.x;
  int m = q >> 6;
  int i0 = (q & 63) << 3;
  size_t eoff = (size_t)(m >> 6) * NIN + i0;
  size_t doff = (size_t)((m >> 14) * U_DIM + (m & 63)) * NIN + i0;
  float4 e0 = *(const float4*)(ep0 + eoff);
  float4 e1 = *(const float4*)(ep0 + eoff + 4);
  float4 f0 = *(const float4*)(ep1 + eoff);
  float4 f1 = *(const float4*)(ep1 + eoff + 4);
  float4 d0 = *(const float4*)(dp0 + doff);
  float4 d1 = *(const float4*)(dp0 + doff + 4);
  float4 g0 = *(const float4*)(dp1 + doff);
  float4 g1 = *(const float4*)(dp1 + doff + 4);
  float4 c0 = *(const float4*)(b1 + i0);
  float4 c1 = *(const float4*)(b1 + i0 + 4);
  float x[8] = { e0.x + f0.x + d0.x + g0.x + c0.x, e0.y + f0.y + d0.y + g0.y + c0.y,
                 e0.z + f0.z + d0.z + g0.z + c0.z, e0.w + f0.w + d0.w + g0.w + c0.w,
                 e1.x + f1.x + d1.x + g1.x + c1.x, e1.y + f1.y + d1.y + g1.y + c1.y,
                 e1.z + f1.z + d1.z + g1.z + c1.z, e1.w + f1.w + d1.w + g1.w + c1.w };
  union { unsigned short s[8]; uint4 u; } o;
#pragma unroll
  for (int j = 0; j < 8; ++j) {
    float ex = __expf(2.0f * x[j]);
    float t = 1.0f - 2.0f / (ex + 1.0f);
    o.s[j] = f2bf(t);
  }
  *(uint4*)(Hb + (size_t)q * 8) = o.u;
}

// ---------------- main GEMM: out = H @ W2b^T + b2 ----------------
// R10 structure (256x128 tile, 4 waves 128x64, 3-stage pipeline A+B in LDS,
// seg-rot swizzle, supertile L2 map, NT stores, 72KB LDS -> 2 blocks/CU) with
// ONE barrier per k-step: vmcnt(6) -> s_barrier -> stage k+2 -> reads -> MFMA.
// WAR safe: iter k-1 reads complete (lgkm) before that wave's MFMAs, which
// precede its barrier-k arrival; stage k+2 (same buf as iter k-1) issues after.
// Counted vmcnt: steady outstanding at wait = stage k+1 (6 loads) -> vmcnt(6);
// k=15 -> vmcnt(0).
__global__ __launch_bounds__(256, 2) void gemm_kernel(const unsigned short* __restrict__ Hb,
                                                      const unsigned short* __restrict__ W2b,
                                                      const float* __restrict__ b2,
                                                      float* __restrict__ out) {
  __shared__ __align__(16) char smem[73728];  // 3 stages x (A 16KB + B 8KB)
  const int tid = threadIdx.x;
  const int lane = tid & 63;
  const int wv = tid >> 6;
  const int wr = wv >> 1, wc = wv & 1;   // wave tile: rows wr*128, cols wc*64
  const int bid = blockIdx.x;

  // XCD chunk + 4x8 supertile mapping (grid 4096 = 8 XCD x 512)
  const int xcd = bid & 7;
  const int idx = bid >> 3;
  const int sup = idx >> 5;
  const int within = idx & 31;
  const int tm = (xcd << 4) | ((sup >> 2) << 2) | (within >> 3);  // 0..127
  const int tn = ((sup & 3) << 3) | (within & 7);                 // 0..31
  const int m0 = tm * 256, n0 = tn * 128;

  // staging source (pre-swizzled seg-rot, proven)
  const int srow = tid >> 2;
  const int segp = ((((tid & 3) - ((tid >> 3) & 3)) & 3) << 3);
  const unsigned short* pA = Hb + (size_t)(m0 + srow) * 512 + segp;
  const unsigned short* pB = W2b + (size_t)(n0 + srow) * 512 + segp;
  const int dstOff = tid << 4;
  // swizzled conflict-free read (proven 0 conflicts)
  const int laneA = ((lane & 15) << 6) | ((((lane >> 4) + ((lane >> 1) & 7)) & 3) << 4);

  f32x4 acc[8][4] = {};
  bf16x8 af[8], bf_[4];

  // b2 first: its 4 loads are the oldest and drain with the first vmcnt(6)
  float b2v[4];
#pragma unroll
  for (int ni = 0; ni < 4; ++ni) b2v[ni] = b2[n0 + wc * 64 + ni * 16 + (lane & 15)];

#define STAGE(T, BUF) do { \
    gload_lds16(pA + (size_t)(T) * 32,                smem + (BUF) * 24576 + dstOff); \
    gload_lds16(pA + (size_t)(T) * 32 + 64 * 512,     smem + (BUF) * 24576 + 4096 + dstOff); \
    gload_lds16(pA + (size_t)(T) * 32 + 128 * 512,    smem + (BUF) * 24576 + 8192 + dstOff); \
    gload_lds16(pA + (size_t)(T) * 32 + 192 * 512,    smem + (BUF) * 24576 + 12288 + dstOff); \
    gload_lds16(pB + (size_t)(T) * 32,                smem + (BUF) * 24576 + 16384 + dstOff); \
    gload_lds16(pB + (size_t)(T) * 32 + 64 * 512,     smem + (BUF) * 24576 + 20480 + dstOff); \
  } while (0)
#define BAR() __builtin_amdgcn_s_barrier()
#define SCHED0() __builtin_amdgcn_sched_barrier(0)
#define VMCNT(N) asm volatile("s_waitcnt vmcnt(" #N ")" ::: "memory")

  STAGE(0, 0);
  STAGE(1, 1);

#pragma unroll
  for (int k = 0; k < 16; ++k) {
    const int cur = k % 3;
    if (k < 15) { VMCNT(6); } else { VMCNT(0); }   // stage k landed (stage k+1 may fly)
    BAR();
    SCHED0();   // pin stage + reads below the barrier
    if (k < 14) { STAGE(k + 2, (k + 2) % 3); }
#pragma unroll
    for (int mi = 0; mi < 8; ++mi)
      af[mi] = *(const bf16x8*)(smem + cur * 24576 + ((wr * 8 + mi) << 10) + laneA);
#pragma unroll
    for (int ni = 0; ni < 4; ++ni)
      bf_[ni] = *(const bf16x8*)(smem + cur * 24576 + 16384 + ((wc * 4 + ni) << 10) + laneA);
    __builtin_amdgcn_s_setprio(1);
#pragma unroll
    for (int mi = 0; mi < 8; ++mi)
#pragma unroll
      for (int ni = 0; ni < 4; ++ni)
        acc[mi][ni] = __builtin_amdgcn_mfma_f32_16x16x32_bf16(af[mi], bf_[ni], acc[mi][ni], 0, 0, 0);
    __builtin_amdgcn_s_setprio(0);
    // no end barrier: next iter's barrier is the WAR fence (reads drained via
    // lgkm deps before each wave's MFMAs, which precede its barrier arrival)
  }

#undef STAGE
#undef BAR
#undef SCHED0
#undef VMCNT

  // epilogue: C = acc + b2, NT stores (keep 512MB stream out of L2/L3 — proven)
#pragma unroll
  for (int mi = 0; mi < 8; ++mi) {
#pragma unroll
    for (int r = 0; r < 4; ++r) {
      int row = m0 + wr * 128 + mi * 16 + ((lane >> 4) << 2) + r;
      float* po = out + (size_t)row * NV + n0 + wc * 64 + (lane & 15);
#pragma unroll
      for (int ni = 0; ni < 4; ++ni)
        __builtin_nontemporal_store(acc[mi][ni][r] + b2v[ni], po + ni * 16);
    }
  }
}

extern "C" void kernel_launch(void* const* d_in, const int* in_sizes, int n_in,
                              void* d_out, int out_size, void* d_ws, size_t ws_size,
                              hipStream_t stream) {
  const float* enc = (const float*)d_in[0];
  const float* dec = (const float*)d_in[1];
  const float* W1  = (const float*)d_in[2];
  const float* b1  = (const float*)d_in[3];
  const float* W2  = (const float*)d_in[4];
  const float* b2  = (const float*)d_in[5];
  float* out = (float*)d_out;

  char* ws = (char*)d_ws;
  unsigned short* W2b = (unsigned short*)(ws);                 // 4 MB
  float* ep0 = (float*)(ws + 4194304);                         // 1 MB
  float* ep1 = (float*)(ws + 5242880);                         // 1 MB
  float* dp0 = (float*)(ws + 6291456);                         // 256 KB
  float* dp1 = (float*)(ws + 6553600);                         // 256 KB
  unsigned short* Hb = (unsigned short*)(ws + 6815744);        // 32 MB

  hipLaunchKernelGGL(prep_kernel, dim3(1064), dim3(256), 0, stream,
                     W2, W2b, enc, dec, W1, ep0, ep1, dp0, dp1);
  hipLaunchKernelGGL(h_kernel, dim3(8192), dim3(256), 0, stream, ep0, ep1, dp0, dp1, b1, Hb);
  hipLaunchKernelGGL(gemm_kernel, dim3(4096), dim3(256), 0, stream, Hb, W2b, b2, out);
}